// Round 1
// baseline (338.245 us; speedup 1.0000x reference)
//
#include <hip/hip_runtime.h>
#include <cstddef>

namespace {

constexpr int B = 4, V = 20000, P = 400000, NN = 50000, MP = 32;
constexpr float GAMMA = 10.0f, INV_GAMMA = 0.1f;
constexpr float KSOFT = 2.0f;
constexpr float THRESH = 1.0f;
constexpr float W_WL = 1.0f, W_CONG = 0.5f;
constexpr int BLOCKS_PER_BATCH = 128;
constexpr int NET_GRID = BLOCKS_PER_BATCH * B;   // 512 blocks, 4 waves each

__device__ __forceinline__ float fast_rcp(float x) { return __builtin_amdgcn_rcpf(x); }
// sigmoid: inf-safe — exp overflow -> inf -> rcp -> 0
__device__ __forceinline__ float sigmoidf(float z) { return fast_rcp(1.0f + __expf(-z)); }

__global__ void zero_ws_kernel(float* __restrict__ p, int n) {
    int i = blockIdx.x * blockDim.x + threadIdx.x;
    if (i < n) p[i] = 0.0f;
}

// rotated = Rm @ off with Rm = [[w0-w2, w3-w1],[w1-w3, w0-w2]]
__global__ void pin_pos_kernel(const float* __restrict__ positions,
                               const int* __restrict__ pin_to_macro,
                               const float* __restrict__ pin_offsets,
                               const float* __restrict__ rot_onehot,
                               float* __restrict__ pin_pos) {
    int idx = blockIdx.x * blockDim.x + threadIdx.x;
    if (idx >= B * P) return;
    int b = idx / P;
    int p = idx - b * P;
    int m = pin_to_macro[p];
    float2 off = ((const float2*)pin_offsets)[p];
    float2 pos = ((const float2*)positions)[(size_t)b * V + m];
    float4 w = ((const float4*)rot_onehot)[(size_t)b * V + m];
    float a = w.x - w.z;   // w0 - w2
    float c = w.y - w.w;   // w1 - w3
    float rx = a * off.x - c * off.y;
    float ry = c * off.x + a * off.y;
    ((float2*)pin_pos)[idx] = make_float2(pos.x + rx, pos.y + ry);
}

// One wave per net. Lane i owns grid row i (y-index); 64-float register row acc.
__global__ void __launch_bounds__(256)
net_kernel(const float* __restrict__ pin_pos,
           const int* __restrict__ net_to_pin,
           const float* __restrict__ net_weights,
           float* __restrict__ rudy,    // B * 64 * 64
           float* __restrict__ hpwl) {  // B
    __shared__ float tile[64 * 65];     // stride 65 -> conflict-free ds_add
    __shared__ float4 xst[4][16];       // per-wave in_x staging (64 floats)

    int x = blockIdx.x;
    int xcd = x & 7;                    // round-robin dispatch heuristic
    int b = xcd >> 1;                   // batch -> XCD pair (L2 locality)
    int sub = ((x >> 3) << 1) | (xcd & 1);   // 0..BLOCKS_PER_BATCH-1
    int tid = threadIdx.x;
    int wave = tid >> 6;
    int lane = tid & 63;

    for (int k = tid; k < 64 * 65; k += 256) tile[k] = 0.0f;
    __syncthreads();

    float acc[64];
    #pragma unroll
    for (int j = 0; j < 64; ++j) acc[j] = 0.0f;
    float hp = 0.0f;

    const float2* pp = (const float2*)(pin_pos + (size_t)b * P * 2);
    float* xrow = (float*)xst[wave];

    const int wstride = BLOCKS_PER_BATCH * 4;
    for (int n = sub * 4 + wave; n < NN; n += wstride) {
        // ---- gather up to 32 pins (lanes 0-31) ----
        float px = 0.0f, py = 0.0f;
        bool valid = false;
        if (lane < MP) {
            int pi = net_to_pin[n * MP + lane];
            if (pi >= 0) {
                valid = true;
                float2 q = pp[pi];
                px = q.x; py = q.y;
            }
        }
        float vxmax = valid ? px : -1e30f;
        float vxmin = valid ? px :  1e30f;
        float vymax = valid ? py : -1e30f;
        float vymin = valid ? py :  1e30f;
        #pragma unroll
        for (int m = 32; m >= 1; m >>= 1) {
            vxmax = fmaxf(vxmax, __shfl_xor(vxmax, m, 64));
            vxmin = fminf(vxmin, __shfl_xor(vxmin, m, 64));
            vymax = fmaxf(vymax, __shfl_xor(vymax, m, 64));
            vymin = fminf(vymin, __shfl_xor(vymin, m, 64));
        }
        // ---- stable LSE sums (invalid lanes contribute exactly 0, matching exp(-1e10)=0) ----
        float ex1 = valid ? __expf(GAMMA * (px - vxmax)) : 0.0f;
        float ex2 = valid ? __expf(GAMMA * (vxmin - px)) : 0.0f;
        float ey1 = valid ? __expf(GAMMA * (py - vymax)) : 0.0f;
        float ey2 = valid ? __expf(GAMMA * (vymin - py)) : 0.0f;
        #pragma unroll
        for (int m = 32; m >= 1; m >>= 1) {
            ex1 += __shfl_xor(ex1, m, 64);
            ex2 += __shfl_xor(ex2, m, 64);
            ey1 += __shfl_xor(ey1, m, 64);
            ey2 += __shfl_xor(ey2, m, 64);
        }
        float wl = (vxmax - vxmin) + (vymax - vymin)
                 + (__logf(ex1) + __logf(ex2) + __logf(ey1) + __logf(ey2)) * INV_GAMMA;
        hp += wl * net_weights[n];

        // ---- bbox in grid coords; (v+1)*0.5*(M-1), M-1 = 63 ----
        float bxmin = (vxmin + 1.0f) * 31.5f;
        float bxmax = (vxmax + 1.0f) * 31.5f;
        float bymin = (vymin + 1.0f) * 31.5f;
        float bymax = (vymax + 1.0f) * 31.5f;
        float inv_size = fast_rcp(
            fmaxf((bxmax - bxmin + 1.0f) * (bymax - bymin + 1.0f), 1.0f));
        float g = (float)lane;
        float inx = sigmoidf(KSOFT * (g - bxmin + 0.5f)) * sigmoidf(KSOFT * (bxmax - g + 0.5f));
        float iny = sigmoidf(KSOFT * (g - bymin + 0.5f)) * sigmoidf(KSOFT * (bymax - g + 0.5f));
        float yv = iny * inv_size;

        // ---- outer product: acc[j] += yv * in_x[j], in_x broadcast via LDS ----
        xrow[lane] = inx;
        asm volatile("s_waitcnt lgkmcnt(0)" ::: "memory");  // wave-private LDS, no barrier needed
        #pragma unroll
        for (int jj = 0; jj < 16; ++jj) {
            float4 xv = xst[wave][jj];   // uniform address -> broadcast ds_read_b128
            acc[4 * jj + 0] = fmaf(yv, xv.x, acc[4 * jj + 0]);
            acc[4 * jj + 1] = fmaf(yv, xv.y, acc[4 * jj + 1]);
            acc[4 * jj + 2] = fmaf(yv, xv.z, acc[4 * jj + 2]);
            acc[4 * jj + 3] = fmaf(yv, xv.w, acc[4 * jj + 3]);
        }
    }

    // ---- block reduce: register rows -> LDS tile (stride-65 pad) ----
    #pragma unroll
    for (int j = 0; j < 64; ++j)
        atomicAdd(&tile[lane * 65 + j], acc[j]);
    if (lane == 0) atomicAdd(&hpwl[b], hp);
    __syncthreads();
    for (int k = tid; k < 4096; k += 256) {
        int i = k >> 6, j = k & 63;
        atomicAdd(&rudy[(size_t)b * 4096 + k], tile[i * 65 + j]);
    }
}

__global__ void conv_penalty_kernel(const float* __restrict__ rudy,
                                    const float* __restrict__ hpwl,
                                    float* __restrict__ out) {
    int b = blockIdx.x;
    __shared__ float tile[64][64];
    __shared__ float ker[49];
    __shared__ float red[4];
    int tid = threadIdx.x;
    if (tid == 0) {
        float g1[7];
        for (int i = 0; i < 7; ++i) { float t = (float)(i - 3); g1[i] = __expf(-t * t / 4.5f); }
        float s = 0.0f;
        for (int i = 0; i < 7; ++i)
            for (int j = 0; j < 7; ++j) s += g1[i] * g1[j];
        float inv = 1.0f / s;
        for (int i = 0; i < 7; ++i)
            for (int j = 0; j < 7; ++j) ker[i * 7 + j] = g1[i] * g1[j] * inv;
    }
    for (int k = tid; k < 4096; k += 256) tile[k >> 6][k & 63] = rudy[b * 4096 + k];
    __syncthreads();
    float pen = 0.0f;
    for (int k = tid; k < 4096; k += 256) {
        int i = k >> 6, j = k & 63;
        float s = 0.0f;
        for (int di = -3; di <= 3; ++di) {
            int ii = i + di;
            if (ii < 0 || ii >= 64) continue;
            #pragma unroll
            for (int dj = -3; dj <= 3; ++dj) {
                int jj = j + dj;
                if (jj < 0 || jj >= 64) continue;
                s += ker[(di + 3) * 7 + (dj + 3)] * tile[ii][jj];
            }
        }
        float ov = s - THRESH;
        if (ov > 0.0f) pen += ov * ov;
    }
    #pragma unroll
    for (int m = 32; m >= 1; m >>= 1) pen += __shfl_xor(pen, m, 64);
    if ((tid & 63) == 0) red[tid >> 6] = pen;
    __syncthreads();
    if (tid == 0) out[b] = W_WL * hpwl[b] + W_CONG * (red[0] + red[1] + red[2] + red[3]);
}

} // namespace

extern "C" void kernel_launch(void* const* d_in, const int* in_sizes, int n_in,
                              void* d_out, int out_size, void* d_ws, size_t ws_size,
                              hipStream_t stream) {
    const float* positions    = (const float*)d_in[0];
    const int*   net_to_pin   = (const int*)d_in[1];
    const int*   pin_to_macro = (const int*)d_in[2];
    const float* pin_offsets  = (const float*)d_in[3];
    const float* rot_onehot   = (const float*)d_in[4];
    const float* net_weights  = (const float*)d_in[5];
    float* out = (float*)d_out;

    // workspace layout: pin_pos (B*P*2 f32 = 12.8 MB) | rudy (B*4096 f32) | hpwl (B f32)
    float* pin_pos = (float*)d_ws;
    float* rudy    = pin_pos + (size_t)B * P * 2;
    float* hpwl    = rudy + (size_t)B * 64 * 64;

    int nz = B * 64 * 64 + B;            // rudy + hpwl are contiguous
    zero_ws_kernel<<<(nz + 255) / 256, 256, 0, stream>>>(rudy, nz);
    pin_pos_kernel<<<(B * P + 255) / 256, 256, 0, stream>>>(
        positions, pin_to_macro, pin_offsets, rot_onehot, pin_pos);
    net_kernel<<<NET_GRID, 256, 0, stream>>>(pin_pos, net_to_pin, net_weights, rudy, hpwl);
    conv_penalty_kernel<<<B, 256, 0, stream>>>(rudy, hpwl, out);
}